// Round 7
// baseline (418.394 us; speedup 1.0000x reference)
//
#include <hip/hip_runtime.h>
#include <stdint.h>

#define KQ     16    // queries per knn block
#define NCHUNK 4     // point chunks per query group
#define CAPC   256   // LDS survivor cap per (query, chunk); E~54 (proven R6)
#define KNB    16

typedef short short8 __attribute__((ext_vector_type(8)));
typedef float floatx4 __attribute__((ext_vector_type(4)));
typedef float floatx2 __attribute__((ext_vector_type(2)));

__device__ __forceinline__ unsigned short f2bf(float x) {
  union { float f; uint32_t u; } v; v.f = x;
  uint32_t u = v.u + 0x7FFFu + ((v.u >> 16) & 1u);   // RNE
  return (unsigned short)(u >> 16);
}
__device__ __forceinline__ float bf2f(unsigned short b) {
  return __uint_as_float(((uint32_t)b) << 16);
}
__device__ __forceinline__ float rfl(float v) {   // wave-uniform -> SGPR
  return __int_as_float(__builtin_amdgcn_readfirstlane(__float_as_int(v)));
}

static __device__ __forceinline__ floatx2 fma2(floatx2 a, floatx2 b, floatx2 c) {
#if __has_builtin(__builtin_elementwise_fma)
  return __builtin_elementwise_fma(a, b, c);
#else
  floatx2 r; r[0] = fmaf(a[0], b[0], c[0]); r[1] = fmaf(a[1], b[1], c[1]);
  return r;
#endif
}
static __device__ __forceinline__ floatx2 min2(floatx2 a, floatx2 b) {
#if __has_builtin(__builtin_elementwise_min)
  return __builtin_elementwise_min(a, b);
#else
  floatx2 r; r[0] = fminf(a[0], b[0]); r[1] = fminf(a[1], b[1]);
  return r;
#endif
}
static __device__ __forceinline__ floatx2 sp2(float v) {
  floatx2 r; r[0] = v; r[1] = v; return r;
}

// ---------------------------------------------------------------------------
// K1 knn: threshold-select over NCHUNK chunks per 16-query group, streaming
// RAW pos (no prep). Pass 1: full chunk scan, tau = max of 16 disjoint group
// mins (+margin) >= chunk t16. Pass 2 (bitwise-identical t) collects idx into
// LDS. Pass 3 extracts the chunk's exact top-16 (d2,idx u64; same fma chain
// so t is bitwise equal to the streamed t) -> cand_out[m][chunk][16].
// Side-job (blocks 0..63): Wt = bf16 W_att^T for K2.
// ---------------------------------------------------------------------------
__global__ __launch_bounds__(256) void knn_kernel(
    const float* __restrict__ pos, const float* __restrict__ W_att,
    const int* __restrict__ idx, unsigned long long* __restrict__ cand_out,
    unsigned short* __restrict__ Wt, int N, int Npad, int M) {
  __shared__ uint32_t cand[KQ][CAPC];
  __shared__ int cnt[KQ];
  __shared__ float gmin[KQ][16];
  __shared__ float tau_s[KQ];

  const int tid = threadIdx.x;
  const int wv = tid >> 6, lane = tid & 63;
  const int qg = blockIdx.x >> 2, chunk = blockIdx.x & 3;
  const int q0 = qg * KQ;
  const int chunkPts = Npad >> 2;          // multiple of 512
  const int iters = chunkPts >> 9;
  const int jbase = chunk * chunkPts;

  // side job: Wt[f][c] = bf16(W_att[c][f])
  if (blockIdx.x < 64) {
    int id = blockIdx.x * 256 + tid;       // < 16384
    int c = id >> 7, f = id & 127;
    Wt[f * 128 + c] = f2bf(W_att[id]);
  }

  float sx[KQ], sy[KQ], sz[KQ], qq[KQ];
#pragma unroll
  for (int qi = 0; qi < KQ; ++qi) {
    int m = q0 + qi; if (m >= M) m = M - 1;
    int ii = idx[m];
    float ax = pos[3 * ii], ay = pos[3 * ii + 1], az = pos[3 * ii + 2];
    sx[qi] = rfl(-2.f * ax); sy[qi] = rfl(-2.f * ay); sz[qi] = rfl(-2.f * az);
    qq[qi] = rfl(fmaf(ax, ax, fmaf(ay, ay, az * az)));
  }
  if (tid < KQ) cnt[tid] = 0;

  // ---- pass 1: full-chunk per-lane t-mins (packed 2 pts: j and j+256) ----
  floatx2 tmn[KQ];
#pragma unroll
  for (int qi = 0; qi < KQ; ++qi) tmn[qi] = sp2(3.4e38f);
  {
    int j0 = jbase + tid;
    int cA = (j0 < N) ? j0 : N - 1, cB = (j0 + 256 < N) ? j0 + 256 : N - 1;
    float x0 = pos[3 * cA], y0 = pos[3 * cA + 1], z0 = pos[3 * cA + 2];
    float x1 = pos[3 * cB], y1 = pos[3 * cB + 1], z1 = pos[3 * cB + 2];
    for (int it = 0; it < iters; ++it) {
      int jn = j0 + 512;
      int nA = (jn < N) ? jn : N - 1, nB = (jn + 256 < N) ? jn + 256 : N - 1;
      float nx0 = pos[3 * nA], ny0 = pos[3 * nA + 1], nz0 = pos[3 * nA + 2];
      float nx1 = pos[3 * nB], ny1 = pos[3 * nB + 1], nz1 = pos[3 * nB + 2];
      floatx2 X, Y, Z;
      X[0] = x0; X[1] = x1; Y[0] = y0; Y[1] = y1; Z[0] = z0; Z[1] = z1;
      floatx2 W = fma2(X, X, fma2(Y, Y, Z * Z));
      W[0] = (j0 < N) ? W[0] : 3.0e38f;
      W[1] = (j0 + 256 < N) ? W[1] : 3.0e38f;
#pragma unroll
      for (int qi = 0; qi < KQ; ++qi) {
        floatx2 t = fma2(sp2(sx[qi]), X,
                         fma2(sp2(sy[qi]), Y, fma2(sp2(sz[qi]), Z, W)));
        tmn[qi] = min2(tmn[qi], t);
      }
      x0 = nx0; y0 = ny0; z0 = nz0; x1 = nx1; y1 = ny1; z1 = nz1; j0 = jn;
    }
  }
  // 16 disjoint thread-groups -> group mins -> tau
#pragma unroll
  for (int qi = 0; qi < KQ; ++qi) {
    float v = fminf(tmn[qi][0], tmn[qi][1]);
    v = fminf(v, __shfl_xor(v, 1));
    v = fminf(v, __shfl_xor(v, 2));
    v = fminf(v, __shfl_xor(v, 4));
    v = fminf(v, __shfl_xor(v, 8));
    if ((tid & 15) == 0) gmin[qi][tid >> 4] = v;
  }
  __syncthreads();
  if (tid < KQ) {
    float t = gmin[tid][0];
#pragma unroll
    for (int g = 1; g < 16; ++g) t = fmaxf(t, gmin[tid][g]);
    tau_s[tid] = t + fabsf(t) * 1e-6f + 1e-7f;
  }
  __syncthreads();
  float tau[KQ];
#pragma unroll
  for (int qi = 0; qi < KQ; ++qi) tau[qi] = rfl(tau_s[qi]);

  // ---- pass 2: re-stream chunk, collect survivor indices ----
  {
    int j0 = jbase + tid;
    int cA = (j0 < N) ? j0 : N - 1, cB = (j0 + 256 < N) ? j0 + 256 : N - 1;
    float x0 = pos[3 * cA], y0 = pos[3 * cA + 1], z0 = pos[3 * cA + 2];
    float x1 = pos[3 * cB], y1 = pos[3 * cB + 1], z1 = pos[3 * cB + 2];
    for (int it = 0; it < iters; ++it) {
      int jn = j0 + 512;
      int nA = (jn < N) ? jn : N - 1, nB = (jn + 256 < N) ? jn + 256 : N - 1;
      float nx0 = pos[3 * nA], ny0 = pos[3 * nA + 1], nz0 = pos[3 * nA + 2];
      float nx1 = pos[3 * nB], ny1 = pos[3 * nB + 1], nz1 = pos[3 * nB + 2];
      floatx2 X, Y, Z;
      X[0] = x0; X[1] = x1; Y[0] = y0; Y[1] = y1; Z[0] = z0; Z[1] = z1;
      floatx2 W = fma2(X, X, fma2(Y, Y, Z * Z));
      W[0] = (j0 < N) ? W[0] : 3.0e38f;
      W[1] = (j0 + 256 < N) ? W[1] : 3.0e38f;
#pragma unroll
      for (int qi = 0; qi < KQ; ++qi) {
        floatx2 t = fma2(sp2(sx[qi]), X,
                         fma2(sp2(sy[qi]), Y, fma2(sp2(sz[qi]), Z, W)));
        if (fminf(t[0], t[1]) <= tau[qi]) {
          if (t[0] <= tau[qi]) {
            int sl = atomicAdd(&cnt[qi], 1);
            if (sl < CAPC) cand[qi][sl] = (uint32_t)j0;
          }
          if (t[1] <= tau[qi]) {
            int sl = atomicAdd(&cnt[qi], 1);
            if (sl < CAPC) cand[qi][sl] = (uint32_t)(j0 + 256);
          }
        }
      }
      x0 = nx0; y0 = ny0; z0 = nz0; x1 = nx1; y1 = ny1; z1 = nz1; j0 = jn;
    }
  }
  __syncthreads();

  // ---- pass 3: per wave 4 queries; exact top-16 of this chunk -> global ----
#pragma unroll
  for (int i = 0; i < 4; ++i) {
    int qi = wv * 4 + i;
    int m = q0 + qi;
    int nc = cnt[qi]; if (nc > CAPC) nc = CAPC;
    unsigned long long c[CAPC / 64];
#pragma unroll
    for (int ch = 0; ch < CAPC / 64; ++ch) {
      c[ch] = ~0ull;
      int s = ch * 64 + lane;
      if (s < nc) {
        uint32_t j = cand[qi][s];
        float px = pos[3 * j], py = pos[3 * j + 1], pz = pos[3 * j + 2];
        float pp = fmaf(px, px, fmaf(py, py, pz * pz));
        float t = fmaf(sx[qi], px, fmaf(sy[qi], py, fmaf(sz[qi], pz, pp)));
        float d2 = fmaxf(qq[qi] + t, 0.f);
        c[ch] = ((unsigned long long)__float_as_uint(d2) << 32) | j;
      }
    }
#pragma unroll
    for (int r = 0; r < KNB; ++r) {
      unsigned long long mn = c[0];
#pragma unroll
      for (int ch = 1; ch < CAPC / 64; ++ch) mn = (c[ch] < mn) ? c[ch] : mn;
#pragma unroll
      for (int off = 1; off < 64; off <<= 1) {
        unsigned long long o = __shfl_xor(mn, off);
        mn = (o < mn) ? o : mn;
      }
      if (m < M && lane == 0)
        cand_out[(size_t)m * 64 + chunk * 16 + r] = mn;
#pragma unroll
      for (int ch = 0; ch < CAPC / 64; ++ch)
        if (c[ch] == mn) c[ch] = ~0ull;
    }
  }
}

// ---------------------------------------------------------------------------
// K2 fused: merge(64 cands -> 16 nbrs) + LocSE + bf16-MFMA attention +
// softmax + mean + out GEMM + relu. 8 queries / 256-thread block.
// ---------------------------------------------------------------------------
__global__ __launch_bounds__(256) void fused_kernel(
    const float* __restrict__ x, const float* __restrict__ pos,
    const int* __restrict__ idx, const float* __restrict__ W_pos,
    const float* __restrict__ b_pos, const unsigned short* __restrict__ Wt,
    const float* __restrict__ b_att, const float* __restrict__ W_glob,
    const float* __restrict__ b_glob,
    const unsigned long long* __restrict__ cand_out,
    float* __restrict__ out, int M) {
  __shared__ __align__(16) unsigned short fijb[8][16][136];
  __shared__ int nbr_s[128];
  __shared__ float qx_s[8], qy_s[8], qz_s[8];
  __shared__ float agg[8][128];

  const int tid = threadIdx.x;
  const int wid = tid >> 6, lane = tid & 63;
  const int col = lane & 15, quad = lane >> 4;
  const int b = blockIdx.x;

  if (tid < 8) {
    int mq = b * 8 + tid; if (mq >= M) mq = M - 1;
    int ii = idx[mq];
    qx_s[tid] = pos[3 * ii]; qy_s[tid] = pos[3 * ii + 1];
    qz_s[tid] = pos[3 * ii + 2];
  }

  // phase 0: merge 4x16 chunk-top16 -> global top-16 (per wave: 2 queries)
#pragma unroll
  for (int i = 0; i < 2; ++i) {
    int q = wid * 2 + i;
    int mq = b * 8 + q; if (mq >= M) mq = M - 1;
    unsigned long long v = cand_out[(size_t)mq * 64 + lane];
#pragma unroll
    for (int r = 0; r < KNB; ++r) {
      unsigned long long mn = v;
#pragma unroll
      for (int off = 1; off < 64; off <<= 1) {
        unsigned long long o = __shfl_xor(mn, off);
        mn = (o < mn) ? o : mn;
      }
      if (lane == 0) nbr_s[q * 16 + r] = (int)(uint32_t)mn;
      if (v == mn) v = ~0ull;
    }
  }
  float wp[10];
#pragma unroll
  for (int t = 0; t < 10; ++t) wp[t] = W_pos[t * 64 + lane];
  float bp = b_pos[lane];
  __syncthreads();

  // phase 1a: x gather (f32 -> bf16), 2 threads per (q,k) row
  {
    int rr = tid >> 1, h = tid & 1;
    int jn = nbr_s[rr];
    const float4* src = (const float4*)(x + (size_t)jn * 64) + h * 8;
    short8* dst = (short8*)&fijb[rr >> 4][rr & 15][h * 32];
#pragma unroll
    for (int i = 0; i < 4; ++i) {
      float4 u = src[2 * i], v = src[2 * i + 1];
      short8 w;
      w[0] = (short)f2bf(u.x); w[1] = (short)f2bf(u.y);
      w[2] = (short)f2bf(u.z); w[3] = (short)f2bf(u.w);
      w[4] = (short)f2bf(v.x); w[5] = (short)f2bf(v.y);
      w[6] = (short)f2bf(v.z); w[7] = (short)f2bf(v.w);
      dst[i] = w;
    }
  }
  // phase 1b: LocSE rij (bf16); wave handles 2 queries, lane = channel
#pragma unroll
  for (int qi = 0; qi < 2; ++qi) {
    int q = wid * 2 + qi;
    float qxv = qx_s[q], qyv = qy_s[q], qzv = qz_s[q];
#pragma unroll 4
    for (int k = 0; k < 16; ++k) {
      int jn = nbr_s[q * 16 + k];
      float px = pos[3 * jn], py = pos[3 * jn + 1], pz = pos[3 * jn + 2];
      float vx = qxv - px, vy = qyv - py, vz = qzv - pz;
      float dd = sqrtf(fmaf(vx, vx, fmaf(vy, vy, vz * vz)));
      float r = bp;
      r = fmaf(qxv, wp[0], r); r = fmaf(qyv, wp[1], r); r = fmaf(qzv, wp[2], r);
      r = fmaf(px, wp[3], r);  r = fmaf(py, wp[4], r);  r = fmaf(pz, wp[5], r);
      r = fmaf(vx, wp[6], r);  r = fmaf(vy, wp[7], r);  r = fmaf(vz, wp[8], r);
      r = fmaf(dd, wp[9], r);
      r = fmaxf(r, 0.f);
      fijb[q][k][64 + lane] = f2bf(r);
    }
  }
  __syncthreads();

  // phase 2: MFMA attention + softmax + mean -> agg (LDS)
#pragma unroll 1
  for (int qi = 0; qi < 2; ++qi) {
    int q = wid * 2 + qi;

    short8 af[4];
#pragma unroll
    for (int cs = 0; cs < 4; ++cs)
      af[cs] = *(const short8*)&fijb[q][col][cs * 32 + quad * 8];

    floatx4 acc[8];
#pragma unroll
    for (int ft = 0; ft < 8; ++ft) {
      float bav = b_att[ft * 16 + col];
      floatx4 a = {bav, bav, bav, bav};
#pragma unroll
      for (int cs = 0; cs < 4; ++cs) {
        short8 bfrag =
            *(const short8*)&Wt[(ft * 16 + col) * 128 + cs * 32 + quad * 8];
        a = __builtin_amdgcn_mfma_f32_16x16x32_bf16(af[cs], bfrag, a, 0, 0, 0);
      }
      acc[ft] = a;
    }

    float rowmax[4], rowinv[4];
#pragma unroll
    for (int r = 0; r < 4; ++r) {
      float mx = acc[0][r];
#pragma unroll
      for (int ft = 1; ft < 8; ++ft) mx = fmaxf(mx, acc[ft][r]);
      mx = fmaxf(mx, __shfl_xor(mx, 1));
      mx = fmaxf(mx, __shfl_xor(mx, 2));
      mx = fmaxf(mx, __shfl_xor(mx, 4));
      mx = fmaxf(mx, __shfl_xor(mx, 8));
      float sm = 0.f;
#pragma unroll
      for (int ft = 0; ft < 8; ++ft) sm += __expf(acc[ft][r] - mx);
      sm += __shfl_xor(sm, 1);
      sm += __shfl_xor(sm, 2);
      sm += __shfl_xor(sm, 4);
      sm += __shfl_xor(sm, 8);
      rowmax[r] = mx;
      rowinv[r] = 1.0f / sm;
    }

#pragma unroll
    for (int ft = 0; ft < 8; ++ft) {
      float ap = 0.f;
#pragma unroll
      for (int r = 0; r < 4; ++r) {
        float s = __expf(acc[ft][r] - rowmax[r]) * rowinv[r];
        float fv = bf2f(fijb[q][quad * 4 + r][ft * 16 + col]);
        ap = fmaf(s, fv, ap);
      }
      ap += __shfl_xor(ap, 16);
      ap += __shfl_xor(ap, 32);
      if (quad == 0) agg[q][ft * 16 + col] = ap * (1.0f / 16.0f);
    }
  }
  __syncthreads();

  // phase 3: out = relu(agg @ W_glob + b_glob); wave rows via readlane bcast
  {
    const int f = tid & 127, h = tid >> 7;   // waves 0,1: rows 0-3; 2,3: 4-7
    float a0[4], a1[4];
#pragma unroll
    for (int i = 0; i < 4; ++i) {
      a0[i] = agg[h * 4 + i][lane];
      a1[i] = agg[h * 4 + i][64 + lane];
    }
    float bg = b_glob[f];
    float acc[4];
#pragma unroll
    for (int i = 0; i < 4; ++i) acc[i] = bg;
#pragma unroll 16
    for (int c = 0; c < 64; ++c) {
      float w = W_glob[c * 128 + f];
#pragma unroll
      for (int i = 0; i < 4; ++i) acc[i] = fmaf(__shfl(a0[i], c), w, acc[i]);
    }
#pragma unroll 16
    for (int c = 0; c < 64; ++c) {
      float w = W_glob[(64 + c) * 128 + f];
#pragma unroll
      for (int i = 0; i < 4; ++i) acc[i] = fmaf(__shfl(a1[i], c), w, acc[i]);
    }
#pragma unroll
    for (int i = 0; i < 4; ++i) {
      int m = b * 8 + h * 4 + i;
      if (m < M) out[m * 128 + f] = fmaxf(acc[i], 0.0f);
    }
  }
}

// ---------------------------------------------------------------------------
extern "C" void kernel_launch(void* const* d_in, const int* in_sizes, int n_in,
                              void* d_out, int out_size, void* d_ws,
                              size_t ws_size, hipStream_t stream) {
  const float* x      = (const float*)d_in[0];
  const float* pos    = (const float*)d_in[1];
  const int*   idx    = (const int*)d_in[2];
  const float* W_pos  = (const float*)d_in[3];
  const float* b_pos  = (const float*)d_in[4];
  const float* W_att  = (const float*)d_in[5];
  const float* b_att  = (const float*)d_in[6];
  const float* W_glob = (const float*)d_in[7];
  const float* b_glob = (const float*)d_in[8];
  float* out = (float*)d_out;

  const int N = in_sizes[1] / 3;
  const int M = in_sizes[2];
  const int Npad = (N + 2047) & ~2047;   // NCHUNK chunks, each mult. of 512

  char* ws = (char*)d_ws;
  size_t o = 0;
  unsigned long long* cand_out = (unsigned long long*)(ws + o);
  o += (((size_t)M * 64 * 8) + 255) & ~(size_t)255;
  unsigned short* Wt = (unsigned short*)(ws + o);
  o += (128 * 128 * 2 + 255) & ~(size_t)255;

  const int QG = (M + KQ - 1) / KQ;
  knn_kernel<<<QG * NCHUNK, 256, 0, stream>>>(pos, W_att, idx, cand_out, Wt,
                                              N, Npad, M);
  fused_kernel<<<(M + 7) / 8, 256, 0, stream>>>(
      x, pos, idx, W_pos, b_pos, Wt, b_att, W_glob, b_glob, cand_out, out, M);
}